// Round 5
// baseline (286.909 us; speedup 1.0000x reference)
//
#include <hip/hip_runtime.h>

// B=8, N=2048, C=512. Flash attention + fp16 MFMA pipeline.
// attn r5: swapped QK^T (S^T, lane-local softmax), P in registers via
// cvt_pkrtz + permlane swaps (no P LDS round-trip), softmax(t) || QK(t+1) ||
// PV(t) overlap, K staged 2 ahead / G 1 ahead, 1 barrier/tile, defer-max,
// XOR-swizzled K staging, XCD-bijective batch swizzle.
// ws layout: xb(16MB) h(16MB) l(16MB) gT(16MB) y(16MB) Wt(2MB)  [fp16 bits]

typedef __attribute__((ext_vector_type(4))) float f32x4;
typedef __attribute__((ext_vector_type(8))) short s16x8;      // fp16 bit-patterns
typedef __attribute__((ext_vector_type(4))) short s16x4;
typedef __attribute__((ext_vector_type(8))) _Float16 f16x8;   // MFMA operand
typedef __attribute__((ext_vector_type(4))) unsigned u32x4;

typedef unsigned int u32;
typedef __attribute__((address_space(1))) const u32 gu32;
typedef __attribute__((address_space(3))) u32 lu32;

__device__ __forceinline__ void gload16(const short* g, short* l) {
  __builtin_amdgcn_global_load_lds((gu32*)g, (lu32*)l, 16, 0, 0);
}

__device__ __forceinline__ short f2h(float f) {
  _Float16 h = (_Float16)f;
  return __builtin_bit_cast(short, h);
}

__device__ __forceinline__ unsigned pk2h(float a, float b) {
  return __builtin_bit_cast(unsigned, __builtin_amdgcn_cvt_pkrtz(a, b));
}

#define MFMA(a, b, c) __builtin_amdgcn_mfma_f32_16x16x32_f16(a, b, c, 0, 0, 0)

// ---------------- conversion kernels ----------------

__global__ __launch_bounds__(256) void conv_x_kernel(const float* __restrict__ x,
                                                     short* __restrict__ xb) {
  int i = blockIdx.x * 256 + threadIdx.x;
  const float4* xv = (const float4*)x;
  float4 a = xv[2 * i], b = xv[2 * i + 1];
  s16x8 o;
  o[0] = f2h(a.x); o[1] = f2h(a.y); o[2] = f2h(a.z); o[3] = f2h(a.w);
  o[4] = f2h(b.x); o[5] = f2h(b.y); o[6] = f2h(b.z); o[7] = f2h(b.w);
  ((s16x8*)xb)[i] = o;
}

__global__ __launch_bounds__(256) void conv_w_kernel(const float* __restrict__ Wh,
                                                     const float* __restrict__ Wl,
                                                     const float* __restrict__ Wg,
                                                     const float* __restrict__ Wm,
                                                     short* __restrict__ Wt) {
  int idx = blockIdx.x * 256 + threadIdx.x;
  int k = idx & 511, n = (idx >> 9) & 511, w = idx >> 18;
  const float* W = (w == 0) ? Wh : (w == 1) ? Wl : (w == 2) ? Wg : Wm;
  Wt[idx] = f2h(W[k * 512 + n]);
}

// ---------------- fused 3-way MLP GEMM ----------------

__global__ __launch_bounds__(256) void mlp3_kernel(const short* __restrict__ A,
                                                   const short* __restrict__ Wt_all,
                                                   const float* __restrict__ bh,
                                                   const float* __restrict__ bl,
                                                   const float* __restrict__ bg,
                                                   short* __restrict__ h,
                                                   short* __restrict__ l,
                                                   short* __restrict__ gT) {
  int z = blockIdx.z;
  const short* Wt = Wt_all + z * 262144;
  const float* bias = (z == 0) ? bh : (z == 1) ? bl : bg;

  __shared__ __align__(16) short lds_a[128 * 40];
  __shared__ __align__(16) short lds_b[128 * 40];
  int tid = threadIdx.x, lane = tid & 63, w = tid >> 6;
  int wm = w >> 1, wn = w & 1;
  int bm = blockIdx.x * 128, bn = blockIdx.y * 128;

  f32x4 acc[4][4];
#pragma unroll
  for (int mi = 0; mi < 4; ++mi)
#pragma unroll
    for (int ni = 0; ni < 4; ++ni) acc[mi][ni] = (f32x4){0.f, 0.f, 0.f, 0.f};

  for (int k0 = 0; k0 < 512; k0 += 32) {
#pragma unroll
    for (int it = 0; it < 2; ++it) {
      int chunk = tid + it * 256;
      int row = chunk >> 2, c8 = (chunk & 3) * 8;
      *(s16x8*)&lds_a[row * 40 + c8] =
          *(const s16x8*)&A[(size_t)(bm + row) * 512 + k0 + c8];
      *(s16x8*)&lds_b[row * 40 + c8] =
          *(const s16x8*)&Wt[(bn + row) * 512 + k0 + c8];
    }
    __syncthreads();
    f16x8 af[4], bfr[4];
#pragma unroll
    for (int mi = 0; mi < 4; ++mi)
      af[mi] = *(const f16x8*)&lds_a[(wm * 64 + mi * 16 + (lane & 15)) * 40 +
                                     (lane >> 4) * 8];
#pragma unroll
    for (int ni = 0; ni < 4; ++ni)
      bfr[ni] = *(const f16x8*)&lds_b[(wn * 64 + ni * 16 + (lane & 15)) * 40 +
                                      (lane >> 4) * 8];
#pragma unroll
    for (int mi = 0; mi < 4; ++mi)
#pragma unroll
      for (int ni = 0; ni < 4; ++ni) acc[mi][ni] = MFMA(af[mi], bfr[ni], acc[mi][ni]);
    __syncthreads();
  }

#pragma unroll
  for (int mi = 0; mi < 4; ++mi)
#pragma unroll
    for (int ni = 0; ni < 4; ++ni) {
      int col = bn + wn * 64 + ni * 16 + (lane & 15);
      float bv = bias[col];
#pragma unroll
      for (int r = 0; r < 4; ++r) {
        int row = bm + wm * 64 + mi * 16 + (lane >> 4) * 4 + r;
        float v = fmaxf(acc[mi][ni][r] + bv, 0.0f);
        short o = f2h(v);
        if (z == 0) h[(size_t)row * 512 + col] = o;
        else if (z == 1) l[(size_t)row * 512 + col] = o;
        else {
          int bb = row >> 11, mm = row & 2047;
          gT[((size_t)bb * 512 + col) * 2048 + mm] = o;
        }
      }
    }
}

// ---------------- flash attention + residual ----------------
// 256 blocks x 256 threads (4 waves x 16 q, full D). KVBLK=32.
// S^T = mfma(K,Q): lane owns query (lane&15), keys (lane>>4)*4+r (+16).
// PV: O^T = mfma(G^T, P^T) with P^T built in-register via permlane swaps.

__global__ __launch_bounds__(256, 1) void attn_kernel(const short* __restrict__ lmat,
                                                      const short* __restrict__ hmat,
                                                      const short* __restrict__ gT,
                                                      const float* __restrict__ x,
                                                      short* __restrict__ y) {
  __shared__ __align__(16) short kbuf[2][16384];  // [32 keys][512], XOR-swizzled
  __shared__ __align__(16) short gbuf[2][16384];  // [512 c][32 keys], linear
  int tid = threadIdx.x, lane = tid & 63, w = tid >> 6;
  int swz = (blockIdx.x & 7) * 32 + (blockIdx.x >> 3);
  int b = swz >> 5, qt = swz & 31;
  int q0 = qt * 64 + w * 16;
  const short* lb = lmat + (size_t)b * 2048 * 512;
  const short* hb = hmat + (size_t)b * 2048 * 512;
  const short* gb = gT + (size_t)b * 512 * 2048;

  int r0 = lane & 15, g = lane >> 4;

  // Q fragments (B-operand: lane&15 = query col, k-chunk g*8): 64 VGPR
  f16x8 qf[16];
  {
    int q = q0 + r0;
#pragma unroll
    for (int ks = 0; ks < 16; ++ks)
      qf[ks] = *(const f16x8*)&lb[(size_t)q * 512 + ks * 32 + g * 8];
  }
  f32x4 accO[32];  // O^T: query r0, d = nf*16 + g*4 + r
#pragma unroll
  for (int i = 0; i < 32; ++i) accO[i] = (f32x4){0.f, 0.f, 0.f, 0.f};
  float mrun = -3e38f, lsumL = 0.f;  // per-lane (one query), partial over g

  auto stageK = [&](int buf, int t) {
    int key0 = t * 32;
    short* kd = &kbuf[buf][0];
#pragma unroll
    for (int j = 0; j < 8; ++j) {
      int wl = w * 8 + j;
      gload16(hb + (size_t)(key0 + wl) * 512 + (((lane * 16) ^ ((wl & 7) << 4)) >> 1),
              kd + wl * 512);
    }
  };
  auto stageG = [&](int buf, int t) {
    int key0 = t * 32;
    short* gd = &gbuf[buf][0];
#pragma unroll
    for (int j = 0; j < 8; ++j) {
      int wl = w * 8 + j;
      int c = wl * 16 + (lane >> 2);
      gload16(gb + (size_t)c * 2048 + key0 + (lane & 3) * 8, gd + wl * 512);
    }
  };
  auto QK = [&](int buf, f32x4& o0, f32x4& o1) {
    const short* kb = &kbuf[buf][0];
#pragma unroll
    for (int ks = 0; ks < 16; ++ks) {
      f16x8 k0f = *(const f16x8*)&kb[(r0 * 512 + ks * 32 + g * 8) ^ ((r0 & 7) << 3)];
      o0 = MFMA(k0f, qf[ks], o0);
      f16x8 k1f = *(const f16x8*)&kb[((r0 + 16) * 512 + ks * 32 + g * 8) ^ ((r0 & 7) << 3)];
      o1 = MFMA(k1f, qf[ks], o1);
    }
  };

  // prologue: K(0),G(0),K(1); QK(0)
  stageK(0, 0); stageG(0, 0); stageK(1, 1);
  __syncthreads();
  f32x4 sc0 = {0.f, 0.f, 0.f, 0.f}, sc1 = {0.f, 0.f, 0.f, 0.f};
  f32x4 sn0, sn1;
  QK(0, sc0, sc1);
  __syncthreads();

  for (int t = 0; t < 64; ++t) {
    // stage K two ahead (into buffer whose K was consumed last step),
    // G one ahead (into buffer whose G was consumed last step)
    if (t < 62) stageK(t & 1, t + 2);
    if (t < 63) stageG((t + 1) & 1, t + 1);

    // QK(t+1) — independent of softmax(t); reads kbuf[(t+1)&1]
    sn0 = (f32x4){0.f, 0.f, 0.f, 0.f};
    sn1 = (f32x4){0.f, 0.f, 0.f, 0.f};
    if (t < 63) {
      __builtin_amdgcn_s_setprio(1);
      QK((t + 1) & 1, sn0, sn1);
      __builtin_amdgcn_s_setprio(0);
    }

    // ---- softmax(t): lane-local over 8 scores + 2 shuffles ----
    float m2 = fmaxf(fmaxf(fmaxf(sc0[0], sc0[1]), fmaxf(sc0[2], sc0[3])),
                     fmaxf(fmaxf(sc1[0], sc1[1]), fmaxf(sc1[2], sc1[3])));
    m2 = fmaxf(m2, __shfl_xor(m2, 16));
    m2 = fmaxf(m2, __shfl_xor(m2, 32));
    bool ok = (m2 <= mrun + 8.0f);  // defer-max THR=8
    if (!__all((int)ok)) {
      float mnew = fmaxf(mrun, m2);
      float s = __expf(mrun - mnew);
      mrun = mnew;
      lsumL *= s;
#pragma unroll
      for (int nf = 0; nf < 32; ++nf) accO[nf] *= s;
    }
    float a0 = __expf(sc0[0] - mrun), a1 = __expf(sc0[1] - mrun);
    float a2 = __expf(sc0[2] - mrun), a3 = __expf(sc0[3] - mrun);
    float b0 = __expf(sc1[0] - mrun), b1 = __expf(sc1[1] - mrun);
    float b2 = __expf(sc1[2] - mrun), b3 = __expf(sc1[3] - mrun);
    lsumL += (a0 + a1) + (a2 + a3) + (b0 + b1) + (b2 + b3);

    // ---- P^T fragment in-register (B-operand: lane r0 = q, k = g*8+j) ----
    unsigned A0 = pk2h(a0, a1), A1 = pk2h(a2, a3);
    unsigned B0 = pk2h(b0, b1), B1 = pk2h(b2, b3);
    asm volatile("v_permlane32_swap_b32 %0, %1" : "+v"(A0), "+v"(B0));
    asm volatile("v_permlane16_swap_b32 %0, %1" : "+v"(A0), "+v"(B0));
    asm volatile("v_permlane32_swap_b32 %0, %1" : "+v"(A1), "+v"(B1));
    asm volatile("v_permlane16_swap_b32 %0, %1" : "+v"(A1), "+v"(B1));
    u32x4 pw = {A0, A1, B0, B1};
    f16x8 pfrag = __builtin_bit_cast(f16x8, pw);

    // ---- PV(t): O^T += G^T-frag x P^T-frag ----
    const short* gp = &gbuf[t & 1][0];
    __builtin_amdgcn_s_setprio(1);
#pragma unroll
    for (int nf = 0; nf < 32; ++nf) {
      f16x8 gf = *(const f16x8*)&gp[(nf * 16 + r0) * 32 + g * 8];
      accO[nf] = MFMA(gf, pfrag, accO[nf]);
    }
    __builtin_amdgcn_s_setprio(0);

    __syncthreads();
    sc0 = sn0; sc1 = sn1;
  }

  // ---- epilogue ----
  float ls = lsumL;
  ls += __shfl_xor(ls, 16);
  ls += __shfl_xor(ls, 32);
  float inv = 1.0f / ls;
  int q = q0 + r0;
#pragma unroll
  for (int nf = 0; nf < 32; ++nf) {
    int d0 = nf * 16 + g * 4;
    float4 xr = *(const float4*)&x[((size_t)b * 2048 + q) * 512 + d0];
    s16x4 o;
    o[0] = f2h(accO[nf][0] * inv + xr.x);
    o[1] = f2h(accO[nf][1] * inv + xr.y);
    o[2] = f2h(accO[nf][2] * inv + xr.z);
    o[3] = f2h(accO[nf][3] * inv + xr.w);
    *(s16x4*)&y[((size_t)b * 2048 + q) * 512 + d0] = o;
  }
}

// ---------------- final GEMM: relu(y @ Wm + bm) -> f32 out ----------------

__global__ __launch_bounds__(256) void final_gemm_kernel(const short* __restrict__ A,
                                                         const short* __restrict__ Wt,
                                                         const float* __restrict__ bias,
                                                         float* __restrict__ out) {
  __shared__ __align__(16) short lds_a[128 * 40];
  __shared__ __align__(16) short lds_b[128 * 40];
  int tid = threadIdx.x, lane = tid & 63, w = tid >> 6;
  int wm = w >> 1, wn = w & 1;
  int bm = blockIdx.x * 128, bn = blockIdx.y * 128;

  f32x4 acc[4][4];
#pragma unroll
  for (int mi = 0; mi < 4; ++mi)
#pragma unroll
    for (int ni = 0; ni < 4; ++ni) acc[mi][ni] = (f32x4){0.f, 0.f, 0.f, 0.f};

  for (int k0 = 0; k0 < 512; k0 += 32) {
#pragma unroll
    for (int it = 0; it < 2; ++it) {
      int chunk = tid + it * 256;
      int row = chunk >> 2, c8 = (chunk & 3) * 8;
      *(s16x8*)&lds_a[row * 40 + c8] =
          *(const s16x8*)&A[(size_t)(bm + row) * 512 + k0 + c8];
      *(s16x8*)&lds_b[row * 40 + c8] =
          *(const s16x8*)&Wt[(bn + row) * 512 + k0 + c8];
    }
    __syncthreads();
    f16x8 af[4], bfr[4];
#pragma unroll
    for (int mi = 0; mi < 4; ++mi)
      af[mi] = *(const f16x8*)&lds_a[(wm * 64 + mi * 16 + (lane & 15)) * 40 +
                                     (lane >> 4) * 8];
#pragma unroll
    for (int ni = 0; ni < 4; ++ni)
      bfr[ni] = *(const f16x8*)&lds_b[(wn * 64 + ni * 16 + (lane & 15)) * 40 +
                                      (lane >> 4) * 8];
#pragma unroll
    for (int mi = 0; mi < 4; ++mi)
#pragma unroll
      for (int ni = 0; ni < 4; ++ni) acc[mi][ni] = MFMA(af[mi], bfr[ni], acc[mi][ni]);
    __syncthreads();
  }

#pragma unroll
  for (int mi = 0; mi < 4; ++mi)
#pragma unroll
    for (int ni = 0; ni < 4; ++ni) {
      int col = bn + wn * 64 + ni * 16 + (lane & 15);
      float bv = bias[col];
#pragma unroll
      for (int r = 0; r < 4; ++r) {
        int row = bm + wm * 64 + mi * 16 + (lane >> 4) * 4 + r;
        out[(size_t)row * 512 + col] = fmaxf(acc[mi][ni][r] + bv, 0.0f);
      }
    }
}

// ---------------- host launch ----------------

extern "C" void kernel_launch(void* const* d_in, const int* in_sizes, int n_in,
                              void* d_out, int out_size, void* d_ws, size_t ws_size,
                              hipStream_t stream) {
  const float* x  = (const float*)d_in[0];
  const float* Wh = (const float*)d_in[1];
  const float* bh = (const float*)d_in[2];
  const float* Wl = (const float*)d_in[3];
  const float* bl = (const float*)d_in[4];
  const float* Wg = (const float*)d_in[5];
  const float* bg = (const float*)d_in[6];
  const float* Wm = (const float*)d_in[7];
  const float* bm = (const float*)d_in[8];

  char* ws = (char*)d_ws;
  const size_t SZ = 16777216;
  short* xb  = (short*)(ws + 0 * SZ);
  short* h   = (short*)(ws + 1 * SZ);
  short* l   = (short*)(ws + 2 * SZ);
  short* gT  = (short*)(ws + 3 * SZ);
  short* y   = (short*)(ws + 4 * SZ);
  short* Wt  = (short*)(ws + 5 * SZ);

  conv_x_kernel<<<4096, 256, 0, stream>>>(x, xb);
  conv_w_kernel<<<4096, 256, 0, stream>>>(Wh, Wl, Wg, Wm, Wt);
  mlp3_kernel<<<dim3(128, 4, 3), 256, 0, stream>>>(xb, Wt, bh, bl, bg, h, l, gT);
  attn_kernel<<<256, 256, 0, stream>>>(l, h, gT, x, y);
  final_gemm_kernel<<<dim3(128, 4), 256, 0, stream>>>(y, Wt + 3 * 262144, bm,
                                                      (float*)d_out);
}